// Round 7
// baseline (80.112 us; speedup 1.0000x reference)
//
#include <hip/hip_runtime.h>
#include <math.h>

#define BB 8
#define NN 256
#define DD 128
#define HH 256
#define LN_EPS 1e-5f

// gelu2(x) = 2*gelu(x) = x + |x|*erf(|x|/sqrt2), branch-free A-S 7.1.26 erf.
// (fold the 0.5 into the consumer's scale factor)
__device__ __forceinline__ float gelu2(float x) {
    const float x2 = x * x;
    const float q  = fmaf(fabsf(x), 0.23164429f, 1.0f);      // 1 + p*|x|/sqrt2
    const float tt = __builtin_amdgcn_rcpf(q);
    const float e  = __builtin_amdgcn_exp2f(x2 * -0.72134752f); // exp(-x^2/2)
    float p = fmaf(tt, 1.061405429f, -1.453152027f);
    p = fmaf(tt, p, 1.421413741f);
    p = fmaf(tt, p, -0.284496736f);
    p = fmaf(tt, p, 0.254829592f);
    const float erf_abs = fmaf(-p * tt, e, 1.0f);
    return fmaf(fabsf(x), erf_abs, x);
}

// Kernel 1: hi = slots @ W_m1[:D] + b_m1 ; hj = slots @ W_m1[D:]
// 4 rows/block, 512 threads (h = t&255, half = t>>8), 512 blocks.
__global__ __launch_bounds__(512, 8) void k_proj_m1(
    const float* __restrict__ slots, const float* __restrict__ W_m1,
    const float* __restrict__ b_m1, float* __restrict__ hi, float* __restrict__ hj)
{
    __shared__ __align__(16) float s[DD][4];
    const int t = threadIdx.x;
    const int h = t & (HH - 1);
    const int half = t >> 8;
    const int row0 = blockIdx.x * 4;
    {   // 512 threads stage 4*128 floats exactly
        const int r = t & 3, d = t >> 2;
        s[d][r] = slots[(row0 + r) * DD + d];
    }
    __syncthreads();
    const float init = half ? 0.0f : b_m1[h];
    float a0 = init, a1 = init, a2 = init, a3 = init;
    const float* __restrict__ W = W_m1 + half * DD * HH + h;
    #pragma unroll 4
    for (int d = 0; d < DD; ++d) {
        const float w = W[d * HH];
        const float4 sv = *(const float4*)&s[d][0];   // broadcast
        a0 = fmaf(sv.x, w, a0);
        a1 = fmaf(sv.y, w, a1);
        a2 = fmaf(sv.z, w, a2);
        a3 = fmaf(sv.w, w, a3);
    }
    float* __restrict__ dst = half ? hj : hi;
    dst[(row0 + 0) * HH + h] = a0;
    dst[(row0 + 1) * HH + h] = a1;
    dst[(row0 + 2) * HH + h] = a2;
    dst[(row0 + 3) * HH + h] = a3;
}

// Kernel 2 (hot): g[b,i,h] = sum_j A[b,i,j]*gelu(hi[b,i,h]+hj[b,j,h]); asum = sum_j A
// 4 i-rows per block, 512 blocks x 512 threads (2 blocks/CU, 16 waves/CU).
// Thread = (jo = t>>6 = j-octant of 32, h0 = (t&63)*4). Each hj b128 load
// feeds 16 gelus (4 h x 4 rows); A via uniform s_loads (SALU, co-issues).
__global__ __launch_bounds__(512, 4) void k_msg_agg(
    const float* __restrict__ adj, const float* __restrict__ hi,
    const float* __restrict__ hj, float* __restrict__ g, float* __restrict__ asum)
{
    __shared__ __align__(16) float pg[8][4][HH];   // 32KB octant partials
    const int t = threadIdx.x;
    const int row0 = blockIdx.x * 4;
    const int b = row0 >> 8;
    const int jo = t >> 6;                  // wave id = j-octant
    const int h0 = (t & 63) * 4;

    if (t < 256) {                          // waves 0-3: adjacency row sums
        const int r = t >> 6, l = t & 63;
        const float* __restrict__ ar = adj + (size_t)(row0 + r) * NN;
        float s1 = ar[l] + ar[l + 64] + ar[l + 128] + ar[l + 192];
        #pragma unroll
        for (int o = 32; o > 0; o >>= 1) s1 += __shfl_down(s1, o, 64);
        if (l == 0) asum[row0 + r] = s1;
    }

    const int jbase = __builtin_amdgcn_readfirstlane(jo * 32);
    const float* __restrict__ A0 = adj + (size_t)(row0 + 0) * NN + jbase;  // uniform
    const float* __restrict__ A1 = A0 + NN;
    const float* __restrict__ A2 = A1 + NN;
    const float* __restrict__ A3 = A2 + NN;
    const float4 hv0 = *(const float4*)(hi + (size_t)(row0 + 0) * HH + h0);
    const float4 hv1 = *(const float4*)(hi + (size_t)(row0 + 1) * HH + h0);
    const float4 hv2 = *(const float4*)(hi + (size_t)(row0 + 2) * HH + h0);
    const float4 hv3 = *(const float4*)(hi + (size_t)(row0 + 3) * HH + h0);
    const float* __restrict__ hjp = hj + ((size_t)b * NN + jbase) * HH + h0;

    float4 ac0 = {0,0,0,0}, ac1 = {0,0,0,0}, ac2 = {0,0,0,0}, ac3 = {0,0,0,0};
    float4 c = *(const float4*)hjp;
    #pragma unroll 2
    for (int jj = 0; jj < 31; ++jj) {
        const float4 n = *(const float4*)(hjp + (size_t)(jj + 1) * HH);  // prefetch
        const float a0 = A0[jj], a1 = A1[jj], a2 = A2[jj], a3 = A3[jj];
        const float gx0 = gelu2(hv0.x + c.x), gy0 = gelu2(hv0.y + c.y),
                    gz0 = gelu2(hv0.z + c.z), gw0 = gelu2(hv0.w + c.w);
        ac0.x = fmaf(a0, gx0, ac0.x); ac0.y = fmaf(a0, gy0, ac0.y);
        ac0.z = fmaf(a0, gz0, ac0.z); ac0.w = fmaf(a0, gw0, ac0.w);
        const float gx1 = gelu2(hv1.x + c.x), gy1 = gelu2(hv1.y + c.y),
                    gz1 = gelu2(hv1.z + c.z), gw1 = gelu2(hv1.w + c.w);
        ac1.x = fmaf(a1, gx1, ac1.x); ac1.y = fmaf(a1, gy1, ac1.y);
        ac1.z = fmaf(a1, gz1, ac1.z); ac1.w = fmaf(a1, gw1, ac1.w);
        const float gx2 = gelu2(hv2.x + c.x), gy2 = gelu2(hv2.y + c.y),
                    gz2 = gelu2(hv2.z + c.z), gw2 = gelu2(hv2.w + c.w);
        ac2.x = fmaf(a2, gx2, ac2.x); ac2.y = fmaf(a2, gy2, ac2.y);
        ac2.z = fmaf(a2, gz2, ac2.z); ac2.w = fmaf(a2, gw2, ac2.w);
        const float gx3 = gelu2(hv3.x + c.x), gy3 = gelu2(hv3.y + c.y),
                    gz3 = gelu2(hv3.z + c.z), gw3 = gelu2(hv3.w + c.w);
        ac3.x = fmaf(a3, gx3, ac3.x); ac3.y = fmaf(a3, gy3, ac3.y);
        ac3.z = fmaf(a3, gz3, ac3.z); ac3.w = fmaf(a3, gw3, ac3.w);
        c = n;
    }
    {   // tail jj = 31
        const float a0 = A0[31], a1 = A1[31], a2 = A2[31], a3 = A3[31];
        ac0.x = fmaf(a0, gelu2(hv0.x + c.x), ac0.x);
        ac0.y = fmaf(a0, gelu2(hv0.y + c.y), ac0.y);
        ac0.z = fmaf(a0, gelu2(hv0.z + c.z), ac0.z);
        ac0.w = fmaf(a0, gelu2(hv0.w + c.w), ac0.w);
        ac1.x = fmaf(a1, gelu2(hv1.x + c.x), ac1.x);
        ac1.y = fmaf(a1, gelu2(hv1.y + c.y), ac1.y);
        ac1.z = fmaf(a1, gelu2(hv1.z + c.z), ac1.z);
        ac1.w = fmaf(a1, gelu2(hv1.w + c.w), ac1.w);
        ac2.x = fmaf(a2, gelu2(hv2.x + c.x), ac2.x);
        ac2.y = fmaf(a2, gelu2(hv2.y + c.y), ac2.y);
        ac2.z = fmaf(a2, gelu2(hv2.z + c.z), ac2.z);
        ac2.w = fmaf(a2, gelu2(hv2.w + c.w), ac2.w);
        ac3.x = fmaf(a3, gelu2(hv3.x + c.x), ac3.x);
        ac3.y = fmaf(a3, gelu2(hv3.y + c.y), ac3.y);
        ac3.z = fmaf(a3, gelu2(hv3.z + c.z), ac3.z);
        ac3.w = fmaf(a3, gelu2(hv3.w + c.w), ac3.w);
    }
    *(float4*)&pg[jo][0][h0] = ac0;
    *(float4*)&pg[jo][1][h0] = ac1;
    *(float4*)&pg[jo][2][h0] = ac2;
    *(float4*)&pg[jo][3][h0] = ac3;
    __syncthreads();
    if (t < 256) {                          // waves 0-3 combine; r = wave id
        const int r = t >> 6, hh0 = (t & 63) * 4;
        float4 s = *(const float4*)&pg[0][r][hh0];
        #pragma unroll
        for (int o = 1; o < 8; ++o) {
            const float4 p = *(const float4*)&pg[o][r][hh0];
            s.x += p.x; s.y += p.y; s.z += p.z; s.w += p.w;
        }
        *(float4*)(g + (size_t)(row0 + r) * HH + hh0) =
            make_float4(0.5f * s.x, 0.5f * s.y, 0.5f * s.z, 0.5f * s.w);
    }
}

// Kernel 3: ag = g@W_m2 + asum*b_m2 ; u = sl@W_u1[:D] + ag@W_u1[D:] + b_u1
//           u = gelu(LN(u)) ; out = slots + u@W_u2 + b_u2
// 8 rows/block, 1024 threads, 256 blocks. Each matmul phase is chunked so
// every W element is loaded exactly ONCE per block (partials in LDS arena).
__global__ __launch_bounds__(1024, 8) void k_update(
    const float* __restrict__ slots, const float* __restrict__ g,
    const float* __restrict__ asum,
    const float* __restrict__ W_m2, const float* __restrict__ b_m2,
    const float* __restrict__ W_u1, const float* __restrict__ b_u1,
    const float* __restrict__ ln_g, const float* __restrict__ ln_b,
    const float* __restrict__ W_u2, const float* __restrict__ b_u2,
    float* __restrict__ out)
{
    __shared__ __align__(16) float gl[HH][8];   // 8KB  gl[h][r]
    __shared__ __align__(16) float sl[DD][8];   // 4KB
    __shared__ __align__(16) float ag[DD][8];   // 4KB
    __shared__ __align__(16) float ul[HH][10];  // 10KB, stride 10 (b64-aligned rows)
    __shared__ float4 red[4][4];
    __shared__ float arena[9216];               // 36KB: pA[8][128][9] / pB[4][256][9]
    const int t = threadIdx.x;
    const int row0 = blockIdx.x * 8;

    for (int k = t; k < 8 * HH; k += 1024) {
        const int r = k & 7, hh = k >> 3;
        gl[hh][r] = g[(row0 + r) * HH + hh];
    }
    for (int k = t; k < 8 * DD; k += 1024) {
        const int r = k & 7, d = k >> 3;
        sl[d][r] = slots[(row0 + r) * DD + d];
    }
    __syncthreads();

    // Phase A: partial ag over hh-chunk. thread (d = t&127, hc = t>>7), 32 hh each.
    {
        const int d = t & (DD - 1), hc = t >> 7;
        float pa[8] = {0, 0, 0, 0, 0, 0, 0, 0};
        const float* __restrict__ W = W_m2 + d;
        const int hh0 = hc * 32;
        #pragma unroll 4
        for (int hh = hh0; hh < hh0 + 32; ++hh) {
            const float w = W[hh * DD];
            const float4 g0 = *(const float4*)&gl[hh][0];   // broadcast
            const float4 g1 = *(const float4*)&gl[hh][4];
            pa[0] = fmaf(g0.x, w, pa[0]); pa[1] = fmaf(g0.y, w, pa[1]);
            pa[2] = fmaf(g0.z, w, pa[2]); pa[3] = fmaf(g0.w, w, pa[3]);
            pa[4] = fmaf(g1.x, w, pa[4]); pa[5] = fmaf(g1.y, w, pa[5]);
            pa[6] = fmaf(g1.z, w, pa[6]); pa[7] = fmaf(g1.w, w, pa[7]);
        }
        float* pw = arena + hc * (DD * 9) + d * 9;
        #pragma unroll
        for (int r = 0; r < 8; ++r) pw[r] = pa[r];
    }
    __syncthreads();
    {   // combine A: thread (d = t&127, r = t>>7)
        const int d = t & (DD - 1), r = t >> 7;
        float acc = asum[row0 + r] * b_m2[d];
        #pragma unroll
        for (int hc = 0; hc < 8; ++hc) acc += arena[hc * (DD * 9) + d * 9 + r];
        ag[d][r] = acc;
    }
    __syncthreads();

    // Phase B: partial u over d-chunk. thread (h = t&255, dc = t>>8), 32 d each.
    {
        const int h = t & (HH - 1), dc = t >> 8;
        float pu[8] = {0, 0, 0, 0, 0, 0, 0, 0};
        const float* __restrict__ W1 = W_u1 + h;
        const float* __restrict__ W2 = W_u1 + DD * HH + h;
        const int d0 = dc * 32;
        #pragma unroll 2
        for (int d = d0; d < d0 + 32; ++d) {
            const float w1 = W1[d * HH];
            const float w2 = W2[d * HH];
            const float4 s0 = *(const float4*)&sl[d][0];
            const float4 s1 = *(const float4*)&sl[d][4];
            const float4 a0 = *(const float4*)&ag[d][0];
            const float4 a1 = *(const float4*)&ag[d][4];
            pu[0] = fmaf(s0.x, w1, pu[0]); pu[0] = fmaf(a0.x, w2, pu[0]);
            pu[1] = fmaf(s0.y, w1, pu[1]); pu[1] = fmaf(a0.y, w2, pu[1]);
            pu[2] = fmaf(s0.z, w1, pu[2]); pu[2] = fmaf(a0.z, w2, pu[2]);
            pu[3] = fmaf(s0.w, w1, pu[3]); pu[3] = fmaf(a0.w, w2, pu[3]);
            pu[4] = fmaf(s1.x, w1, pu[4]); pu[4] = fmaf(a1.x, w2, pu[4]);
            pu[5] = fmaf(s1.y, w1, pu[5]); pu[5] = fmaf(a1.y, w2, pu[5]);
            pu[6] = fmaf(s1.z, w1, pu[6]); pu[6] = fmaf(a1.z, w2, pu[6]);
            pu[7] = fmaf(s1.w, w1, pu[7]); pu[7] = fmaf(a1.w, w2, pu[7]);
        }
        float* pw = arena + dc * (HH * 9) + h * 9;
        #pragma unroll
        for (int r = 0; r < 8; ++r) pw[r] = pu[r];
    }
    __syncthreads();

    // combine B + LayerNorm + gelu. thread (h = t&255, rg = t>>8) rows {2rg, 2rg+1}.
    const int h = t & (HH - 1), rg = t >> 8;
    {
        float u0 = b_u1[h], u1 = u0;
        #pragma unroll
        for (int dc = 0; dc < 4; ++dc) {
            u0 += arena[dc * (HH * 9) + h * 9 + 2 * rg];
            u1 += arena[dc * (HH * 9) + h * 9 + 2 * rg + 1];
        }
        float s1a = u0, s2a = u0 * u0, s1b = u1, s2b = u1 * u1;
        #pragma unroll
        for (int o = 32; o > 0; o >>= 1) {
            s1a += __shfl_xor(s1a, o, 64);
            s2a += __shfl_xor(s2a, o, 64);
            s1b += __shfl_xor(s1b, o, 64);
            s2b += __shfl_xor(s2b, o, 64);
        }
        if ((t & 63) == 0) red[rg][(t >> 6) & 3] = make_float4(s1a, s2a, s1b, s2b);
        __syncthreads();
        const float4 r0 = red[rg][0], r1 = red[rg][1], r2 = red[rg][2], r3 = red[rg][3];
        const float lgv = ln_g[h], lbv = ln_b[h];
        const float t1a = r0.x + r1.x + r2.x + r3.x;
        const float t2a = r0.y + r1.y + r2.y + r3.y;
        const float t1b = r0.z + r1.z + r2.z + r3.z;
        const float t2b = r0.w + r1.w + r2.w + r3.w;
        const float mu0 = t1a * (1.0f / HH);
        const float var0 = t2a * (1.0f / HH) - mu0 * mu0;
        const float mu1 = t1b * (1.0f / HH);
        const float var1 = t2b * (1.0f / HH) - mu1 * mu1;
        ul[h][2 * rg]     = 0.5f * gelu2((u0 - mu0) * rsqrtf(var0 + LN_EPS) * lgv + lbv);
        ul[h][2 * rg + 1] = 0.5f * gelu2((u1 - mu1) * rsqrtf(var1 + LN_EPS) * lgv + lbv);
    }
    __syncthreads();

    // Phase D: partial out over hh-chunk. thread (d = t&127, hc = t>>7), 32 hh each.
    {
        const int d = t & (DD - 1), hc = t >> 7;
        float pd[8] = {0, 0, 0, 0, 0, 0, 0, 0};
        const float* __restrict__ W = W_u2 + d;
        const int hh0 = hc * 32;
        #pragma unroll 4
        for (int hh = hh0; hh < hh0 + 32; ++hh) {
            const float w = W[hh * DD];
            const float2 u01 = *(const float2*)&ul[hh][0];   // broadcast b64 x4
            const float2 u23 = *(const float2*)&ul[hh][2];
            const float2 u45 = *(const float2*)&ul[hh][4];
            const float2 u67 = *(const float2*)&ul[hh][6];
            pd[0] = fmaf(u01.x, w, pd[0]); pd[1] = fmaf(u01.y, w, pd[1]);
            pd[2] = fmaf(u23.x, w, pd[2]); pd[3] = fmaf(u23.y, w, pd[3]);
            pd[4] = fmaf(u45.x, w, pd[4]); pd[5] = fmaf(u45.y, w, pd[5]);
            pd[6] = fmaf(u67.x, w, pd[6]); pd[7] = fmaf(u67.y, w, pd[7]);
        }
        float* pw = arena + hc * (DD * 9) + d * 9;
        #pragma unroll
        for (int r = 0; r < 8; ++r) pw[r] = pd[r];
    }
    __syncthreads();
    {   // combine D: thread (d = t&127, r = t>>7)
        const int d = t & (DD - 1), r = t >> 7;
        float acc = b_u2[d];
        #pragma unroll
        for (int hc = 0; hc < 8; ++hc) acc += arena[hc * (DD * 9) + d * 9 + r];
        out[(row0 + r) * DD + d] = sl[d][r] + acc;
    }
}

extern "C" void kernel_launch(void* const* d_in, const int* in_sizes, int n_in,
                              void* d_out, int out_size, void* d_ws, size_t ws_size,
                              hipStream_t stream) {
    const float* slots = (const float*)d_in[0];
    const float* adj   = (const float*)d_in[1];
    const float* W_m1  = (const float*)d_in[2];
    const float* b_m1  = (const float*)d_in[3];
    const float* W_m2  = (const float*)d_in[4];
    const float* b_m2  = (const float*)d_in[5];
    const float* W_u1  = (const float*)d_in[6];
    const float* b_u1  = (const float*)d_in[7];
    const float* ln_g  = (const float*)d_in[8];
    const float* ln_b  = (const float*)d_in[9];
    const float* W_u2  = (const float*)d_in[10];
    const float* b_u2  = (const float*)d_in[11];
    float* out = (float*)d_out;
    float* ws  = (float*)d_ws;

    const int rows = BB * NN;            // 2048
    float* hi   = ws;
    float* hj   = hi + (size_t)rows * HH;
    float* g    = hj + (size_t)rows * HH;
    float* asum = g  + (size_t)rows * HH;

    hipLaunchKernelGGL(k_proj_m1, dim3(rows / 4), dim3(512), 0, stream,
                       slots, W_m1, b_m1, hi, hj);
    hipLaunchKernelGGL(k_msg_agg, dim3(rows / 4), dim3(512), 0, stream,
                       adj, hi, hj, g, asum);
    hipLaunchKernelGGL(k_update, dim3(rows / 8), dim3(1024), 0, stream,
                       slots, g, asum, W_m2, b_m2, W_u1, b_u1,
                       ln_g, ln_b, W_u2, b_u2, out);
}

// Round 8
// 74.674 us; speedup vs baseline: 1.0728x; 1.0728x over previous
//
#include <hip/hip_runtime.h>
#include <math.h>

#define BB 8
#define NN 256
#define DD 128
#define HH 256
#define LN_EPS 1e-5f

// gelu2(x) = 2*gelu(x) = x + |x|*erf(|x|/sqrt2), branch-free A-S 7.1.26 erf.
// Used for the k_update epilogue and to build the PWL table (not the hot loop).
__device__ __forceinline__ float gelu2(float x) {
    const float x2 = x * x;
    const float q  = fmaf(fabsf(x), 0.23164429f, 1.0f);
    const float tt = __builtin_amdgcn_rcpf(q);
    const float e  = __builtin_amdgcn_exp2f(x2 * -0.72134752f);
    float p = fmaf(tt, 1.061405429f, -1.453152027f);
    p = fmaf(tt, p, 1.421413741f);
    p = fmaf(tt, p, -0.284496736f);
    p = fmaf(tt, p, 0.254829592f);
    const float erf_abs = fmaf(-p * tt, e, 1.0f);
    return fmaf(fabsf(x), erf_abs, x);
}

// Kernel 1: hi = slots @ W_m1[:D] + b_m1 ; hj = slots @ W_m1[D:]
__global__ __launch_bounds__(512, 8) void k_proj_m1(
    const float* __restrict__ slots, const float* __restrict__ W_m1,
    const float* __restrict__ b_m1, float* __restrict__ hi, float* __restrict__ hj)
{
    __shared__ __align__(16) float s[DD][4];
    const int t = threadIdx.x;
    const int h = t & (HH - 1);
    const int half = t >> 8;
    const int row0 = blockIdx.x * 4;
    {
        const int r = t & 3, d = t >> 2;
        s[d][r] = slots[(row0 + r) * DD + d];
    }
    __syncthreads();
    const float init = half ? 0.0f : b_m1[h];
    float a0 = init, a1 = init, a2 = init, a3 = init;
    const float* __restrict__ W = W_m1 + half * DD * HH + h;
    #pragma unroll 4
    for (int d = 0; d < DD; ++d) {
        const float w = W[d * HH];
        const float4 sv = *(const float4*)&s[d][0];
        a0 = fmaf(sv.x, w, a0);
        a1 = fmaf(sv.y, w, a1);
        a2 = fmaf(sv.z, w, a2);
        a3 = fmaf(sv.w, w, a3);
    }
    float* __restrict__ dst = half ? hj : hi;
    dst[(row0 + 0) * HH + h] = a0;
    dst[(row0 + 1) * HH + h] = a1;
    dst[(row0 + 2) * HH + h] = a2;
    dst[(row0 + 3) * HH + h] = a3;
}

// One PWL gelu-core step: T(|xs|) via slope/intercept LDS tables, plus the
// linear part accumulated separately. 18 issue cycles, no transcendentals.
#define GEL(A_, hv_, ce_, accT_, accL_) {                        \
    const float xs_ = (hv_) + (ce_);                             \
    const float ax_ = fabsf(xs_);                                \
    unsigned u_ = (unsigned)(ax_ * 100.0f);                      \
    u_ = u_ < 511u ? u_ : 511u;                                  \
    const float T_ = fmaf(tab[u_], ax_, tab[512 + u_]);          \
    accT_ = fmaf(A_, T_, accT_);                                 \
    accL_ = fmaf(A_, xs_, accL_); }

// Kernel 2 (hot): g[b,i,h] = sum_j A[b,i,j]*gelu(hi[b,i,h]+hj[b,j,h]); asum = sum_j A
// 2 rows/block, 1024 blocks x 256 threads (4 waves = j-quarters of 64).
// gelu via 512-seg PWL table of T(a)=a*erf(a/sqrt2); gelu = 0.5*(x + T(|x|)).
__global__ __launch_bounds__(256, 4) void k_msg_agg(
    const float* __restrict__ adj, const float* __restrict__ hi,
    const float* __restrict__ hj, float* __restrict__ g, float* __restrict__ asum)
{
    __shared__ __align__(16) float tab[1024];    // slope[0:512) icpt[512:1024)
    __shared__ __align__(16) float pg[3][2][HH]; // 6KB partials from jq=1..3
    const int t = threadIdx.x;
    const int row0 = blockIdx.x * 2;
    const int b = row0 >> 8;
    const int jq = t >> 6;                       // wave id = j-quarter
    const int h0 = (t & 63) * 4;

    // Build PWL table: T(a) = gelu2(a) - a on [0, 5.12), 512 segments.
    for (int k = t; k < 512; k += 256) {
        const float a0 = (float)k * 0.01f;
        const float a1 = a0 + 0.01f;
        const float T0 = gelu2(a0) - a0;
        const float T1 = gelu2(a1) - a1;
        const float sl = (T1 - T0) * 100.0f;
        tab[k] = sl;
        tab[512 + k] = fmaf(-sl, a0, T0);
    }
    if (t < 128) {                               // waves 0-1: adjacency row sums
        const int r = t >> 6, l = t & 63;
        const float* __restrict__ ar = adj + (size_t)(row0 + r) * NN;
        float s1 = ar[l] + ar[l + 64] + ar[l + 128] + ar[l + 192];
        #pragma unroll
        for (int o = 32; o > 0; o >>= 1) s1 += __shfl_down(s1, o, 64);
        if (l == 0) asum[row0 + r] = s1;
    }
    __syncthreads();

    const int jbase = __builtin_amdgcn_readfirstlane(jq * 64);
    const float* __restrict__ A0 = adj + (size_t)(row0 + 0) * NN + jbase;  // uniform
    const float* __restrict__ A1 = A0 + NN;
    const float4 hv0 = *(const float4*)(hi + (size_t)(row0 + 0) * HH + h0);
    const float4 hv1 = *(const float4*)(hi + (size_t)(row0 + 1) * HH + h0);
    const float* __restrict__ hjp = hj + ((size_t)b * NN + jbase) * HH + h0;

    float4 t0 = {0,0,0,0}, l0 = {0,0,0,0}, t1 = {0,0,0,0}, l1 = {0,0,0,0};
    float4 c0 = *(const float4*)(hjp);
    float4 c1 = *(const float4*)(hjp + HH);
    #pragma unroll 2
    for (int jj = 0; jj < 62; jj += 2) {
        const float4 n0 = *(const float4*)(hjp + (size_t)(jj + 2) * HH);
        const float4 n1 = *(const float4*)(hjp + (size_t)(jj + 3) * HH);
        const float Aa0 = A0[jj], Ab0 = A1[jj];          // s_load (SALU)
        const float Aa1 = A0[jj + 1], Ab1 = A1[jj + 1];
        GEL(Aa0, hv0.x, c0.x, t0.x, l0.x)
        GEL(Aa0, hv0.y, c0.y, t0.y, l0.y)
        GEL(Aa0, hv0.z, c0.z, t0.z, l0.z)
        GEL(Aa0, hv0.w, c0.w, t0.w, l0.w)
        GEL(Ab0, hv1.x, c0.x, t1.x, l1.x)
        GEL(Ab0, hv1.y, c0.y, t1.y, l1.y)
        GEL(Ab0, hv1.z, c0.z, t1.z, l1.z)
        GEL(Ab0, hv1.w, c0.w, t1.w, l1.w)
        GEL(Aa1, hv0.x, c1.x, t0.x, l0.x)
        GEL(Aa1, hv0.y, c1.y, t0.y, l0.y)
        GEL(Aa1, hv0.z, c1.z, t0.z, l0.z)
        GEL(Aa1, hv0.w, c1.w, t0.w, l0.w)
        GEL(Ab1, hv1.x, c1.x, t1.x, l1.x)
        GEL(Ab1, hv1.y, c1.y, t1.y, l1.y)
        GEL(Ab1, hv1.z, c1.z, t1.z, l1.z)
        GEL(Ab1, hv1.w, c1.w, t1.w, l1.w)
        c0 = n0; c1 = n1;
    }
    {   // tail j = 62, 63 (no prefetch)
        const float Aa0 = A0[62], Ab0 = A1[62];
        const float Aa1 = A0[63], Ab1 = A1[63];
        GEL(Aa0, hv0.x, c0.x, t0.x, l0.x)
        GEL(Aa0, hv0.y, c0.y, t0.y, l0.y)
        GEL(Aa0, hv0.z, c0.z, t0.z, l0.z)
        GEL(Aa0, hv0.w, c0.w, t0.w, l0.w)
        GEL(Ab0, hv1.x, c0.x, t1.x, l1.x)
        GEL(Ab0, hv1.y, c0.y, t1.y, l1.y)
        GEL(Ab0, hv1.z, c0.z, t1.z, l1.z)
        GEL(Ab0, hv1.w, c0.w, t1.w, l1.w)
        GEL(Aa1, hv0.x, c1.x, t0.x, l0.x)
        GEL(Aa1, hv0.y, c1.y, t0.y, l0.y)
        GEL(Aa1, hv0.z, c1.z, t0.z, l0.z)
        GEL(Aa1, hv0.w, c1.w, t0.w, l0.w)
        GEL(Ab1, hv1.x, c1.x, t1.x, l1.x)
        GEL(Ab1, hv1.y, c1.y, t1.y, l1.y)
        GEL(Ab1, hv1.z, c1.z, t1.z, l1.z)
        GEL(Ab1, hv1.w, c1.w, t1.w, l1.w)
    }

    const float4 s0 = make_float4(t0.x + l0.x, t0.y + l0.y, t0.z + l0.z, t0.w + l0.w);
    const float4 s1 = make_float4(t1.x + l1.x, t1.y + l1.y, t1.z + l1.z, t1.w + l1.w);
    if (jq) {
        *(float4*)&pg[jq - 1][0][h0] = s0;
        *(float4*)&pg[jq - 1][1][h0] = s1;
    }
    __syncthreads();
    if (!jq) {
        const float4 p00 = *(const float4*)&pg[0][0][h0];
        const float4 p10 = *(const float4*)&pg[1][0][h0];
        const float4 p20 = *(const float4*)&pg[2][0][h0];
        const float4 p01 = *(const float4*)&pg[0][1][h0];
        const float4 p11 = *(const float4*)&pg[1][1][h0];
        const float4 p21 = *(const float4*)&pg[2][1][h0];
        *(float4*)(g + (size_t)(row0 + 0) * HH + h0) =
            make_float4(0.5f * (s0.x + p00.x + p10.x + p20.x),
                        0.5f * (s0.y + p00.y + p10.y + p20.y),
                        0.5f * (s0.z + p00.z + p10.z + p20.z),
                        0.5f * (s0.w + p00.w + p10.w + p20.w));
        *(float4*)(g + (size_t)(row0 + 1) * HH + h0) =
            make_float4(0.5f * (s1.x + p01.x + p11.x + p21.x),
                        0.5f * (s1.y + p01.y + p11.y + p21.y),
                        0.5f * (s1.z + p01.z + p11.z + p21.z),
                        0.5f * (s1.w + p01.w + p11.w + p21.w));
    }
}

// Kernel 3: ag = g@W_m2 + asum*b_m2 ; u = sl@W_u1[:D] + ag@W_u1[D:] + b_u1
//           u = gelu(LN(u)) ; out = slots + u@W_u2 + b_u2
__global__ __launch_bounds__(1024, 8) void k_update(
    const float* __restrict__ slots, const float* __restrict__ g,
    const float* __restrict__ asum,
    const float* __restrict__ W_m2, const float* __restrict__ b_m2,
    const float* __restrict__ W_u1, const float* __restrict__ b_u1,
    const float* __restrict__ ln_g, const float* __restrict__ ln_b,
    const float* __restrict__ W_u2, const float* __restrict__ b_u2,
    float* __restrict__ out)
{
    __shared__ __align__(16) float gl[HH][8];
    __shared__ __align__(16) float sl[DD][8];
    __shared__ __align__(16) float ag[DD][8];
    __shared__ __align__(16) float ul[HH][10];
    __shared__ float4 red[4][4];
    __shared__ float arena[9216];
    const int t = threadIdx.x;
    const int row0 = blockIdx.x * 8;

    for (int k = t; k < 8 * HH; k += 1024) {
        const int r = k & 7, hh = k >> 3;
        gl[hh][r] = g[(row0 + r) * HH + hh];
    }
    for (int k = t; k < 8 * DD; k += 1024) {
        const int r = k & 7, d = k >> 3;
        sl[d][r] = slots[(row0 + r) * DD + d];
    }
    __syncthreads();

    {
        const int d = t & (DD - 1), hc = t >> 7;
        float pa[8] = {0, 0, 0, 0, 0, 0, 0, 0};
        const float* __restrict__ W = W_m2 + d;
        const int hh0 = hc * 32;
        #pragma unroll 4
        for (int hh = hh0; hh < hh0 + 32; ++hh) {
            const float w = W[hh * DD];
            const float4 g0 = *(const float4*)&gl[hh][0];
            const float4 g1 = *(const float4*)&gl[hh][4];
            pa[0] = fmaf(g0.x, w, pa[0]); pa[1] = fmaf(g0.y, w, pa[1]);
            pa[2] = fmaf(g0.z, w, pa[2]); pa[3] = fmaf(g0.w, w, pa[3]);
            pa[4] = fmaf(g1.x, w, pa[4]); pa[5] = fmaf(g1.y, w, pa[5]);
            pa[6] = fmaf(g1.z, w, pa[6]); pa[7] = fmaf(g1.w, w, pa[7]);
        }
        float* pw = arena + hc * (DD * 9) + d * 9;
        #pragma unroll
        for (int r = 0; r < 8; ++r) pw[r] = pa[r];
    }
    __syncthreads();
    {
        const int d = t & (DD - 1), r = t >> 7;
        float acc = asum[row0 + r] * b_m2[d];
        #pragma unroll
        for (int hc = 0; hc < 8; ++hc) acc += arena[hc * (DD * 9) + d * 9 + r];
        ag[d][r] = acc;
    }
    __syncthreads();

    {
        const int h = t & (HH - 1), dc = t >> 8;
        float pu[8] = {0, 0, 0, 0, 0, 0, 0, 0};
        const float* __restrict__ W1 = W_u1 + h;
        const float* __restrict__ W2 = W_u1 + DD * HH + h;
        const int d0 = dc * 32;
        #pragma unroll 2
        for (int d = d0; d < d0 + 32; ++d) {
            const float w1 = W1[d * HH];
            const float w2 = W2[d * HH];
            const float4 s0 = *(const float4*)&sl[d][0];
            const float4 s1 = *(const float4*)&sl[d][4];
            const float4 a0 = *(const float4*)&ag[d][0];
            const float4 a1 = *(const float4*)&ag[d][4];
            pu[0] = fmaf(s0.x, w1, pu[0]); pu[0] = fmaf(a0.x, w2, pu[0]);
            pu[1] = fmaf(s0.y, w1, pu[1]); pu[1] = fmaf(a0.y, w2, pu[1]);
            pu[2] = fmaf(s0.z, w1, pu[2]); pu[2] = fmaf(a0.z, w2, pu[2]);
            pu[3] = fmaf(s0.w, w1, pu[3]); pu[3] = fmaf(a0.w, w2, pu[3]);
            pu[4] = fmaf(s1.x, w1, pu[4]); pu[4] = fmaf(a1.x, w2, pu[4]);
            pu[5] = fmaf(s1.y, w1, pu[5]); pu[5] = fmaf(a1.y, w2, pu[5]);
            pu[6] = fmaf(s1.z, w1, pu[6]); pu[6] = fmaf(a1.z, w2, pu[6]);
            pu[7] = fmaf(s1.w, w1, pu[7]); pu[7] = fmaf(a1.w, w2, pu[7]);
        }
        float* pw = arena + dc * (HH * 9) + h * 9;
        #pragma unroll
        for (int r = 0; r < 8; ++r) pw[r] = pu[r];
    }
    __syncthreads();

    const int h = t & (HH - 1), rg = t >> 8;
    {
        float u0 = b_u1[h], u1 = u0;
        #pragma unroll
        for (int dc = 0; dc < 4; ++dc) {
            u0 += arena[dc * (HH * 9) + h * 9 + 2 * rg];
            u1 += arena[dc * (HH * 9) + h * 9 + 2 * rg + 1];
        }
        float s1a = u0, s2a = u0 * u0, s1b = u1, s2b = u1 * u1;
        #pragma unroll
        for (int o = 32; o > 0; o >>= 1) {
            s1a += __shfl_xor(s1a, o, 64);
            s2a += __shfl_xor(s2a, o, 64);
            s1b += __shfl_xor(s1b, o, 64);
            s2b += __shfl_xor(s2b, o, 64);
        }
        if ((t & 63) == 0) red[rg][(t >> 6) & 3] = make_float4(s1a, s2a, s1b, s2b);
        __syncthreads();
        const float4 r0 = red[rg][0], r1 = red[rg][1], r2 = red[rg][2], r3 = red[rg][3];
        const float lgv = ln_g[h], lbv = ln_b[h];
        const float t1a = r0.x + r1.x + r2.x + r3.x;
        const float t2a = r0.y + r1.y + r2.y + r3.y;
        const float t1b = r0.z + r1.z + r2.z + r3.z;
        const float t2b = r0.w + r1.w + r2.w + r3.w;
        const float mu0 = t1a * (1.0f / HH);
        const float var0 = t2a * (1.0f / HH) - mu0 * mu0;
        const float mu1 = t1b * (1.0f / HH);
        const float var1 = t2b * (1.0f / HH) - mu1 * mu1;
        ul[h][2 * rg]     = 0.5f * gelu2((u0 - mu0) * rsqrtf(var0 + LN_EPS) * lgv + lbv);
        ul[h][2 * rg + 1] = 0.5f * gelu2((u1 - mu1) * rsqrtf(var1 + LN_EPS) * lgv + lbv);
    }
    __syncthreads();

    {
        const int d = t & (DD - 1), hc = t >> 7;
        float pd[8] = {0, 0, 0, 0, 0, 0, 0, 0};
        const float* __restrict__ W = W_u2 + d;
        const int hh0 = hc * 32;
        #pragma unroll 4
        for (int hh = hh0; hh < hh0 + 32; ++hh) {
            const float w = W[hh * DD];
            const float2 u01 = *(const float2*)&ul[hh][0];
            const float2 u23 = *(const float2*)&ul[hh][2];
            const float2 u45 = *(const float2*)&ul[hh][4];
            const float2 u67 = *(const float2*)&ul[hh][6];
            pd[0] = fmaf(u01.x, w, pd[0]); pd[1] = fmaf(u01.y, w, pd[1]);
            pd[2] = fmaf(u23.x, w, pd[2]); pd[3] = fmaf(u23.y, w, pd[3]);
            pd[4] = fmaf(u45.x, w, pd[4]); pd[5] = fmaf(u45.y, w, pd[5]);
            pd[6] = fmaf(u67.x, w, pd[6]); pd[7] = fmaf(u67.y, w, pd[7]);
        }
        float* pw = arena + hc * (DD * 9) + d * 9;
        #pragma unroll
        for (int r = 0; r < 8; ++r) pw[r] = pd[r];
    }
    __syncthreads();
    {
        const int d = t & (DD - 1), r = t >> 7;
        float acc = b_u2[d];
        #pragma unroll
        for (int hc = 0; hc < 8; ++hc) acc += arena[hc * (DD * 9) + d * 9 + r];
        out[(row0 + r) * DD + d] = sl[d][r] + acc;
    }
}

extern "C" void kernel_launch(void* const* d_in, const int* in_sizes, int n_in,
                              void* d_out, int out_size, void* d_ws, size_t ws_size,
                              hipStream_t stream) {
    const float* slots = (const float*)d_in[0];
    const float* adj   = (const float*)d_in[1];
    const float* W_m1  = (const float*)d_in[2];
    const float* b_m1  = (const float*)d_in[3];
    const float* W_m2  = (const float*)d_in[4];
    const float* b_m2  = (const float*)d_in[5];
    const float* W_u1  = (const float*)d_in[6];
    const float* b_u1  = (const float*)d_in[7];
    const float* ln_g  = (const float*)d_in[8];
    const float* ln_b  = (const float*)d_in[9];
    const float* W_u2  = (const float*)d_in[10];
    const float* b_u2  = (const float*)d_in[11];
    float* out = (float*)d_out;
    float* ws  = (float*)d_ws;

    const int rows = BB * NN;            // 2048
    float* hi   = ws;
    float* hj   = hi + (size_t)rows * HH;
    float* g    = hj + (size_t)rows * HH;
    float* asum = g  + (size_t)rows * HH;

    hipLaunchKernelGGL(k_proj_m1, dim3(rows / 4), dim3(512), 0, stream,
                       slots, W_m1, b_m1, hi, hj);
    hipLaunchKernelGGL(k_msg_agg, dim3(rows / 2), dim3(256), 0, stream,
                       adj, hi, hj, g, asum);
    hipLaunchKernelGGL(k_update, dim3(rows / 8), dim3(1024), 0, stream,
                       slots, g, asum, W_m2, b_m2, W_u1, b_u1,
                       ln_g, ln_b, W_u2, b_u2, out);
}

// Round 9
// 63.791 us; speedup vs baseline: 1.2559x; 1.1706x over previous
//
#include <hip/hip_runtime.h>
#include <math.h>

#define BB 8
#define NN 256
#define DD 128
#define HH 256
#define LN_EPS 1e-5f

// gelu2(x) = 2*gelu(x) = x + |x|*erf(|x|/sqrt2), branch-free A-S 7.1.26 erf.
// Used for the k_update epilogue and to build the PWL table (not the hot loop).
__device__ __forceinline__ float gelu2(float x) {
    const float x2 = x * x;
    const float q  = fmaf(fabsf(x), 0.23164429f, 1.0f);
    const float tt = __builtin_amdgcn_rcpf(q);
    const float e  = __builtin_amdgcn_exp2f(x2 * -0.72134752f);
    float p = fmaf(tt, 1.061405429f, -1.453152027f);
    p = fmaf(tt, p, 1.421413741f);
    p = fmaf(tt, p, -0.284496736f);
    p = fmaf(tt, p, 0.254829592f);
    const float erf_abs = fmaf(-p * tt, e, 1.0f);
    return fmaf(fabsf(x), erf_abs, x);
}

// Kernel 1: hi = slots @ W_m1[:D] + b_m1 ; hj = slots @ W_m1[D:]
__global__ __launch_bounds__(512, 8) void k_proj_m1(
    const float* __restrict__ slots, const float* __restrict__ W_m1,
    const float* __restrict__ b_m1, float* __restrict__ hi, float* __restrict__ hj)
{
    __shared__ __align__(16) float s[DD][4];
    const int t = threadIdx.x;
    const int h = t & (HH - 1);
    const int half = t >> 8;
    const int row0 = blockIdx.x * 4;
    {
        const int r = t & 3, d = t >> 2;
        s[d][r] = slots[(row0 + r) * DD + d];
    }
    __syncthreads();
    const float init = half ? 0.0f : b_m1[h];
    float a0 = init, a1 = init, a2 = init, a3 = init;
    const float* __restrict__ W = W_m1 + half * DD * HH + h;
    #pragma unroll 4
    for (int d = 0; d < DD; ++d) {
        const float w = W[d * HH];
        const float4 sv = *(const float4*)&s[d][0];
        a0 = fmaf(sv.x, w, a0);
        a1 = fmaf(sv.y, w, a1);
        a2 = fmaf(sv.z, w, a2);
        a3 = fmaf(sv.w, w, a3);
    }
    float* __restrict__ dst = half ? hj : hi;
    dst[(row0 + 0) * HH + h] = a0;
    dst[(row0 + 1) * HH + h] = a1;
    dst[(row0 + 2) * HH + h] = a2;
    dst[(row0 + 3) * HH + h] = a3;
}

// One PWL-gelu step: direct symmetric table [-5.12, 5.12), Delta=0.04.
// gelu(xs) = slope[seg]*xs + icpt[seg], (slope,icpt) fetched as one b64.
// cvt_u32_f32 saturates negatives to 0 -> free low clamp.
#define GEL(A_, hv_, ce_, acc_) {                                \
    const float xs_ = (hv_) + (ce_);                             \
    unsigned u_ = (unsigned)fmaf(xs_, 25.0f, 128.0f);            \
    u_ = u_ < 255u ? u_ : 255u;                                  \
    const float2 se_ = tab2[u_ * 16 + cidx];                     \
    acc_ = fmaf(A_, fmaf(se_.x, xs_, se_.y), acc_); }

// Kernel 2 (hot): g[b,i,h] = sum_j A[b,i,j]*gelu(hi[b,i,h]+hj[b,j,h]); asum = sum_j A
// 2 rows/block, 1024 blocks x 256 threads (4 waves = j-quarters of 64).
// 16-way bank-replicated (slope,icpt) float2 table: lane l reads copy l&15 ->
// deterministic <=4-way bank-pair access, single ds_read_b64 per gelu.
__global__ __launch_bounds__(256, 4) void k_msg_agg(
    const float* __restrict__ adj, const float* __restrict__ hi,
    const float* __restrict__ hj, float* __restrict__ g, float* __restrict__ asum)
{
    __shared__ __align__(16) float2 tab2[256 * 16];   // 32KB replicated PWL table
    __shared__ __align__(16) float pg[3][2][HH];      // 6KB partials from jq=1..3
    const int t = threadIdx.x;
    const int row0 = blockIdx.x * 2;
    const int b = row0 >> 8;
    const int jq = t >> 6;                       // wave id = j-quarter
    const int h0 = (t & 63) * 4;
    const int cidx = t & 15;                     // table copy for this lane

    {   // Build table: 256 threads -> one segment each, 16 copies.
        const float x0 = (float)t * 0.04f - 5.12f;
        const float x1 = x0 + 0.04f;
        const float g0 = 0.5f * gelu2(x0);
        const float g1 = 0.5f * gelu2(x1);
        const float sl = (g1 - g0) * 25.0f;
        const float2 v = make_float2(sl, fmaf(-sl, x0, g0));
        #pragma unroll
        for (int c = 0; c < 16; ++c) tab2[t * 16 + c] = v;
    }
    if (t < 128) {                               // waves 0-1: adjacency row sums
        const int r = t >> 6, l = t & 63;
        const float* __restrict__ ar = adj + (size_t)(row0 + r) * NN;
        float s1 = ar[l] + ar[l + 64] + ar[l + 128] + ar[l + 192];
        #pragma unroll
        for (int o = 32; o > 0; o >>= 1) s1 += __shfl_down(s1, o, 64);
        if (l == 0) asum[row0 + r] = s1;
    }
    __syncthreads();

    const int jbase = __builtin_amdgcn_readfirstlane(jq * 64);
    const float* __restrict__ A0 = adj + (size_t)(row0 + 0) * NN + jbase;  // uniform
    const float* __restrict__ A1 = A0 + NN;
    const float4 hv0 = *(const float4*)(hi + (size_t)(row0 + 0) * HH + h0);
    const float4 hv1 = *(const float4*)(hi + (size_t)(row0 + 1) * HH + h0);
    const float* __restrict__ hjp = hj + ((size_t)b * NN + jbase) * HH + h0;

    float4 t0 = {0,0,0,0}, t1 = {0,0,0,0};
    float4 c0 = *(const float4*)(hjp);
    float4 c1 = *(const float4*)(hjp + HH);
    #pragma unroll 2
    for (int jj = 0; jj < 62; jj += 2) {
        const float4 n0 = *(const float4*)(hjp + (size_t)(jj + 2) * HH);
        const float4 n1 = *(const float4*)(hjp + (size_t)(jj + 3) * HH);
        const float Aa0 = A0[jj], Ab0 = A1[jj];          // s_load (SALU)
        const float Aa1 = A0[jj + 1], Ab1 = A1[jj + 1];
        GEL(Aa0, hv0.x, c0.x, t0.x)
        GEL(Aa0, hv0.y, c0.y, t0.y)
        GEL(Aa0, hv0.z, c0.z, t0.z)
        GEL(Aa0, hv0.w, c0.w, t0.w)
        GEL(Ab0, hv1.x, c0.x, t1.x)
        GEL(Ab0, hv1.y, c0.y, t1.y)
        GEL(Ab0, hv1.z, c0.z, t1.z)
        GEL(Ab0, hv1.w, c0.w, t1.w)
        GEL(Aa1, hv0.x, c1.x, t0.x)
        GEL(Aa1, hv0.y, c1.y, t0.y)
        GEL(Aa1, hv0.z, c1.z, t0.z)
        GEL(Aa1, hv0.w, c1.w, t0.w)
        GEL(Ab1, hv1.x, c1.x, t1.x)
        GEL(Ab1, hv1.y, c1.y, t1.y)
        GEL(Ab1, hv1.z, c1.z, t1.z)
        GEL(Ab1, hv1.w, c1.w, t1.w)
        c0 = n0; c1 = n1;
    }
    {   // tail j = 62, 63 (no prefetch)
        const float Aa0 = A0[62], Ab0 = A1[62];
        const float Aa1 = A0[63], Ab1 = A1[63];
        GEL(Aa0, hv0.x, c0.x, t0.x)
        GEL(Aa0, hv0.y, c0.y, t0.y)
        GEL(Aa0, hv0.z, c0.z, t0.z)
        GEL(Aa0, hv0.w, c0.w, t0.w)
        GEL(Ab0, hv1.x, c0.x, t1.x)
        GEL(Ab0, hv1.y, c0.y, t1.y)
        GEL(Ab0, hv1.z, c0.z, t1.z)
        GEL(Ab0, hv1.w, c0.w, t1.w)
        GEL(Aa1, hv0.x, c1.x, t0.x)
        GEL(Aa1, hv0.y, c1.y, t0.y)
        GEL(Aa1, hv0.z, c1.z, t0.z)
        GEL(Aa1, hv0.w, c1.w, t0.w)
        GEL(Ab1, hv1.x, c1.x, t1.x)
        GEL(Ab1, hv1.y, c1.y, t1.y)
        GEL(Ab1, hv1.z, c1.z, t1.z)
        GEL(Ab1, hv1.w, c1.w, t1.w)
    }

    if (jq) {
        *(float4*)&pg[jq - 1][0][h0] = t0;
        *(float4*)&pg[jq - 1][1][h0] = t1;
    }
    __syncthreads();
    if (!jq) {
        const float4 p00 = *(const float4*)&pg[0][0][h0];
        const float4 p10 = *(const float4*)&pg[1][0][h0];
        const float4 p20 = *(const float4*)&pg[2][0][h0];
        const float4 p01 = *(const float4*)&pg[0][1][h0];
        const float4 p11 = *(const float4*)&pg[1][1][h0];
        const float4 p21 = *(const float4*)&pg[2][1][h0];
        *(float4*)(g + (size_t)(row0 + 0) * HH + h0) =
            make_float4(t0.x + p00.x + p10.x + p20.x,
                        t0.y + p00.y + p10.y + p20.y,
                        t0.z + p00.z + p10.z + p20.z,
                        t0.w + p00.w + p10.w + p20.w);
        *(float4*)(g + (size_t)(row0 + 1) * HH + h0) =
            make_float4(t1.x + p01.x + p11.x + p21.x,
                        t1.y + p01.y + p11.y + p21.y,
                        t1.z + p01.z + p11.z + p21.z,
                        t1.w + p01.w + p11.w + p21.w);
    }
}

// Kernel 3: ag = g@W_m2 + asum*b_m2 ; u = sl@W_u1[:D] + ag@W_u1[D:] + b_u1
//           u = gelu(LN(u)) ; out = slots + u@W_u2 + b_u2
__global__ __launch_bounds__(1024, 8) void k_update(
    const float* __restrict__ slots, const float* __restrict__ g,
    const float* __restrict__ asum,
    const float* __restrict__ W_m2, const float* __restrict__ b_m2,
    const float* __restrict__ W_u1, const float* __restrict__ b_u1,
    const float* __restrict__ ln_g, const float* __restrict__ ln_b,
    const float* __restrict__ W_u2, const float* __restrict__ b_u2,
    float* __restrict__ out)
{
    __shared__ __align__(16) float gl[HH][8];
    __shared__ __align__(16) float sl[DD][8];
    __shared__ __align__(16) float ag[DD][8];
    __shared__ __align__(16) float ul[HH][10];
    __shared__ float4 red[4][4];
    __shared__ float arena[9216];
    const int t = threadIdx.x;
    const int row0 = blockIdx.x * 8;

    for (int k = t; k < 8 * HH; k += 1024) {
        const int r = k & 7, hh = k >> 3;
        gl[hh][r] = g[(row0 + r) * HH + hh];
    }
    for (int k = t; k < 8 * DD; k += 1024) {
        const int r = k & 7, d = k >> 3;
        sl[d][r] = slots[(row0 + r) * DD + d];
    }
    __syncthreads();

    {
        const int d = t & (DD - 1), hc = t >> 7;
        float pa[8] = {0, 0, 0, 0, 0, 0, 0, 0};
        const float* __restrict__ W = W_m2 + d;
        const int hh0 = hc * 32;
        #pragma unroll 4
        for (int hh = hh0; hh < hh0 + 32; ++hh) {
            const float w = W[hh * DD];
            const float4 g0 = *(const float4*)&gl[hh][0];
            const float4 g1 = *(const float4*)&gl[hh][4];
            pa[0] = fmaf(g0.x, w, pa[0]); pa[1] = fmaf(g0.y, w, pa[1]);
            pa[2] = fmaf(g0.z, w, pa[2]); pa[3] = fmaf(g0.w, w, pa[3]);
            pa[4] = fmaf(g1.x, w, pa[4]); pa[5] = fmaf(g1.y, w, pa[5]);
            pa[6] = fmaf(g1.z, w, pa[6]); pa[7] = fmaf(g1.w, w, pa[7]);
        }
        float* pw = arena + hc * (DD * 9) + d * 9;
        #pragma unroll
        for (int r = 0; r < 8; ++r) pw[r] = pa[r];
    }
    __syncthreads();
    {
        const int d = t & (DD - 1), r = t >> 7;
        float acc = asum[row0 + r] * b_m2[d];
        #pragma unroll
        for (int hc = 0; hc < 8; ++hc) acc += arena[hc * (DD * 9) + d * 9 + r];
        ag[d][r] = acc;
    }
    __syncthreads();

    {
        const int h = t & (HH - 1), dc = t >> 8;
        float pu[8] = {0, 0, 0, 0, 0, 0, 0, 0};
        const float* __restrict__ W1 = W_u1 + h;
        const float* __restrict__ W2 = W_u1 + DD * HH + h;
        const int d0 = dc * 32;
        #pragma unroll 2
        for (int d = d0; d < d0 + 32; ++d) {
            const float w1 = W1[d * HH];
            const float w2 = W2[d * HH];
            const float4 s0 = *(const float4*)&sl[d][0];
            const float4 s1 = *(const float4*)&sl[d][4];
            const float4 a0 = *(const float4*)&ag[d][0];
            const float4 a1 = *(const float4*)&ag[d][4];
            pu[0] = fmaf(s0.x, w1, pu[0]); pu[0] = fmaf(a0.x, w2, pu[0]);
            pu[1] = fmaf(s0.y, w1, pu[1]); pu[1] = fmaf(a0.y, w2, pu[1]);
            pu[2] = fmaf(s0.z, w1, pu[2]); pu[2] = fmaf(a0.z, w2, pu[2]);
            pu[3] = fmaf(s0.w, w1, pu[3]); pu[3] = fmaf(a0.w, w2, pu[3]);
            pu[4] = fmaf(s1.x, w1, pu[4]); pu[4] = fmaf(a1.x, w2, pu[4]);
            pu[5] = fmaf(s1.y, w1, pu[5]); pu[5] = fmaf(a1.y, w2, pu[5]);
            pu[6] = fmaf(s1.z, w1, pu[6]); pu[6] = fmaf(a1.z, w2, pu[6]);
            pu[7] = fmaf(s1.w, w1, pu[7]); pu[7] = fmaf(a1.w, w2, pu[7]);
        }
        float* pw = arena + dc * (HH * 9) + h * 9;
        #pragma unroll
        for (int r = 0; r < 8; ++r) pw[r] = pu[r];
    }
    __syncthreads();

    const int h = t & (HH - 1), rg = t >> 8;
    {
        float u0 = b_u1[h], u1 = u0;
        #pragma unroll
        for (int dc = 0; dc < 4; ++dc) {
            u0 += arena[dc * (HH * 9) + h * 9 + 2 * rg];
            u1 += arena[dc * (HH * 9) + h * 9 + 2 * rg + 1];
        }
        float s1a = u0, s2a = u0 * u0, s1b = u1, s2b = u1 * u1;
        #pragma unroll
        for (int o = 32; o > 0; o >>= 1) {
            s1a += __shfl_xor(s1a, o, 64);
            s2a += __shfl_xor(s2a, o, 64);
            s1b += __shfl_xor(s1b, o, 64);
            s2b += __shfl_xor(s2b, o, 64);
        }
        if ((t & 63) == 0) red[rg][(t >> 6) & 3] = make_float4(s1a, s2a, s1b, s2b);
        __syncthreads();
        const float4 r0 = red[rg][0], r1 = red[rg][1], r2 = red[rg][2], r3 = red[rg][3];
        const float lgv = ln_g[h], lbv = ln_b[h];
        const float t1a = r0.x + r1.x + r2.x + r3.x;
        const float t2a = r0.y + r1.y + r2.y + r3.y;
        const float t1b = r0.z + r1.z + r2.z + r3.z;
        const float t2b = r0.w + r1.w + r2.w + r3.w;
        const float mu0 = t1a * (1.0f / HH);
        const float var0 = t2a * (1.0f / HH) - mu0 * mu0;
        const float mu1 = t1b * (1.0f / HH);
        const float var1 = t2b * (1.0f / HH) - mu1 * mu1;
        ul[h][2 * rg]     = 0.5f * gelu2((u0 - mu0) * rsqrtf(var0 + LN_EPS) * lgv + lbv);
        ul[h][2 * rg + 1] = 0.5f * gelu2((u1 - mu1) * rsqrtf(var1 + LN_EPS) * lgv + lbv);
    }
    __syncthreads();

    {
        const int d = t & (DD - 1), hc = t >> 7;
        float pd[8] = {0, 0, 0, 0, 0, 0, 0, 0};
        const float* __restrict__ W = W_u2 + d;
        const int hh0 = hc * 32;
        #pragma unroll 4
        for (int hh = hh0; hh < hh0 + 32; ++hh) {
            const float w = W[hh * DD];
            const float2 u01 = *(const float2*)&ul[hh][0];
            const float2 u23 = *(const float2*)&ul[hh][2];
            const float2 u45 = *(const float2*)&ul[hh][4];
            const float2 u67 = *(const float2*)&ul[hh][6];
            pd[0] = fmaf(u01.x, w, pd[0]); pd[1] = fmaf(u01.y, w, pd[1]);
            pd[2] = fmaf(u23.x, w, pd[2]); pd[3] = fmaf(u23.y, w, pd[3]);
            pd[4] = fmaf(u45.x, w, pd[4]); pd[5] = fmaf(u45.y, w, pd[5]);
            pd[6] = fmaf(u67.x, w, pd[6]); pd[7] = fmaf(u67.y, w, pd[7]);
        }
        float* pw = arena + hc * (DD * 9) + d * 9;
        #pragma unroll
        for (int r = 0; r < 8; ++r) pw[r] = pd[r];
    }
    __syncthreads();
    {
        const int d = t & (DD - 1), r = t >> 7;
        float acc = b_u2[d];
        #pragma unroll
        for (int hc = 0; hc < 8; ++hc) acc += arena[hc * (DD * 9) + d * 9 + r];
        out[(row0 + r) * DD + d] = sl[d][r] + acc;
    }
}

extern "C" void kernel_launch(void* const* d_in, const int* in_sizes, int n_in,
                              void* d_out, int out_size, void* d_ws, size_t ws_size,
                              hipStream_t stream) {
    const float* slots = (const float*)d_in[0];
    const float* adj   = (const float*)d_in[1];
    const float* W_m1  = (const float*)d_in[2];
    const float* b_m1  = (const float*)d_in[3];
    const float* W_m2  = (const float*)d_in[4];
    const float* b_m2  = (const float*)d_in[5];
    const float* W_u1  = (const float*)d_in[6];
    const float* b_u1  = (const float*)d_in[7];
    const float* ln_g  = (const float*)d_in[8];
    const float* ln_b  = (const float*)d_in[9];
    const float* W_u2  = (const float*)d_in[10];
    const float* b_u2  = (const float*)d_in[11];
    float* out = (float*)d_out;
    float* ws  = (float*)d_ws;

    const int rows = BB * NN;            // 2048
    float* hi   = ws;
    float* hj   = hi + (size_t)rows * HH;
    float* g    = hj + (size_t)rows * HH;
    float* asum = g  + (size_t)rows * HH;

    hipLaunchKernelGGL(k_proj_m1, dim3(rows / 4), dim3(512), 0, stream,
                       slots, W_m1, b_m1, hi, hj);
    hipLaunchKernelGGL(k_msg_agg, dim3(rows / 2), dim3(256), 0, stream,
                       adj, hi, hj, g, asum);
    hipLaunchKernelGGL(k_update, dim3(rows / 8), dim3(1024), 0, stream,
                       slots, g, asum, W_m2, b_m2, W_u1, b_u1,
                       ln_g, ln_b, W_u2, b_u2, out);
}